// Round 1
// baseline (76.367 us; speedup 1.0000x reference)
//
#include <hip/hip_runtime.h>
#include <math.h>

#define NN 256
#define DD 256
#define KK 16
#define M_MARGIN 0.6f
#define T_THRESH 0.0025f
#define EPS 1e-12f

// Kernel 1: row-wise L2 normalize yi and yi_t into workspace; zero the output
// accumulator (block 0). Grid = 512 blocks (256 rows x 2 matrices), 256 threads.
__global__ void __launch_bounds__(256) normalize_kernel(
    const float* __restrict__ yi, const float* __restrict__ yit,
    float* __restrict__ yin, float* __restrict__ yitn,
    float* __restrict__ out)
{
    const int row  = blockIdx.x & (NN - 1);
    const bool a   = blockIdx.x < NN;
    const float* src = a ? yi  : yit;
    float*       dst = a ? yin : yitn;
    const int t = threadIdx.x;

    float v = src[row * DD + t];
    float s = v * v;
    #pragma unroll
    for (int off = 32; off > 0; off >>= 1) s += __shfl_down(s, off, 64);

    __shared__ float ws[4];
    if ((t & 63) == 0) ws[t >> 6] = s;
    __syncthreads();
    float total = ws[0] + ws[1] + ws[2] + ws[3];

    dst[row * DD + t] = v / sqrtf(total + EPS);

    if (blockIdx.x == 0 && t == 0) out[0] = 0.0f;
}

// Kernel 2: one block per row i. Thread t owns candidate j = t.
//  - dis[i][j]   = 0.5*sqrt(||yin_i - yin_j||^2 + EPS)   (into LDS)
//  - dist[i][j]  = 0.5*sqrt(||yitn_i - yin_j||^2 + EPS)  (into LDS)
//  - stable rank of dis[i][t] among the row (== top_k position).
//    rank in [1,KK]  -> e1 term; rank == 1 -> e2 hinge term.
//  - block-reduce, one atomicAdd per block.
__global__ void __launch_bounds__(256) blcd_main_kernel(
    const float* __restrict__ yin, const float* __restrict__ yitn,
    float* __restrict__ out)
{
    __shared__ float s_yi[DD];
    __shared__ float s_yit[DD];
    __shared__ float sdis[NN];
    __shared__ float sdist[NN];
    __shared__ float lds4[4];
    __shared__ float s_disiit;

    const int i = blockIdx.x;
    const int t = threadIdx.x;

    s_yi[t]  = yin [i * DD + t];
    s_yit[t] = yitn[i * DD + t];
    __syncthreads();

    // dis_yi_yi_t for this row
    {
        float df = s_yi[t] - s_yit[t];
        float v  = df * df;
        #pragma unroll
        for (int off = 32; off > 0; off >>= 1) v += __shfl_down(v, off, 64);
        if ((t & 63) == 0) lds4[t >> 6] = v;
        __syncthreads();
        if (t == 0)
            s_disiit = 0.5f * sqrtf(lds4[0] + lds4[1] + lds4[2] + lds4[3] + EPS);
    }

    // distances from row i (and its tilde) to every row j = t
    const float* rowj = yin + t * DD;
    float d2 = 0.0f, dt2 = 0.0f;
    #pragma unroll 8
    for (int d = 0; d < DD; ++d) {
        float b = rowj[d];
        float u = s_yi[d]  - b;
        float w = s_yit[d] - b;
        d2  += u * u;
        dt2 += w * w;
    }
    sdis[t]  = 0.5f * sqrtf(d2  + EPS);
    sdist[t] = 0.5f * sqrtf(dt2 + EPS);
    __syncthreads();   // also orders s_disiit write before its readers below

    // stable rank (matches jax.lax.top_k tie-break: lower index first)
    const float myv = sdis[t];
    int rank = 0;
    for (int j = 0; j < NN; ++j) {
        float vj = sdis[j];                 // LDS broadcast read
        rank += (vj < myv || (vj == myv && j < t)) ? 1 : 0;
    }

    float contrib = 0.0f;
    if (rank >= 1 && rank <= KK) {
        float dd = myv - sdist[t];
        contrib = dd * dd - T_THRESH;       // e1 term
    }
    if (rank == 1) {
        float o = s_disiit + M_MARGIN - myv;
        contrib += fmaxf(o, 0.0f);          // e2 term
    }

    // block reduce + single atomic per block
    #pragma unroll
    for (int off = 32; off > 0; off >>= 1) contrib += __shfl_down(contrib, off, 64);
    __syncthreads();                        // lds4 reuse safety
    if ((t & 63) == 0) lds4[t >> 6] = contrib;
    __syncthreads();
    if (t == 0) atomicAdd(out, lds4[0] + lds4[1] + lds4[2] + lds4[3]);
}

extern "C" void kernel_launch(void* const* d_in, const int* in_sizes, int n_in,
                              void* d_out, int out_size, void* d_ws, size_t ws_size,
                              hipStream_t stream) {
    (void)in_sizes; (void)n_in; (void)out_size; (void)ws_size;

    const float* yi  = (const float*)d_in[0];
    const float* yit = (const float*)d_in[1];
    float* out = (float*)d_out;

    float* yin  = (float*)d_ws;                 // 256*256 floats
    float* yitn = (float*)d_ws + NN * DD;       // 256*256 floats

    normalize_kernel<<<2 * NN, 256, 0, stream>>>(yi, yit, yin, yitn, out);
    blcd_main_kernel<<<NN, 256, 0, stream>>>(yin, yitn, out);
}

// Round 2
// 74.768 us; speedup vs baseline: 1.0214x; 1.0214x over previous
//
#include <hip/hip_runtime.h>
#include <math.h>

#define NN 256
#define DD 256
#define KK 16
#define M_MARGIN 0.6f
#define T_THRESH 0.0025f
#define EPS 1e-12f

// One fused kernel: block i handles row i; thread t owns candidate j = t.
// Uses the Gram identity ||a_i - a_j||^2 = 2 - 2*(y_i.y_j)/(n_i*n_j) for
// L2-normalized a, so no normalized matrices are ever materialized.
__global__ void __launch_bounds__(256) blcd_fused_kernel(
    const float* __restrict__ yi, const float* __restrict__ yit,
    float* __restrict__ out)
{
    __shared__ float s_yi[DD];    // raw row i
    __shared__ float s_yit[DD];   // raw row i (tilde)
    __shared__ float sdis[NN];    // dis_yii[i][:]
    __shared__ float red[12];     // 4 wave partials x 3 reduced quantities

    const int i = blockIdx.x;
    const int t = threadIdx.x;

    const float a = yi [i * DD + t];
    const float b = yit[i * DD + t];
    s_yi[t]  = a;
    s_yit[t] = b;

    // Block-reduce ||y_i||^2, ||yt_i||^2, y_i.yt_i (3 values at once).
    float r0 = a * a, r1 = b * b, r2 = a * b;
    #pragma unroll
    for (int off = 32; off > 0; off >>= 1) {
        r0 += __shfl_down(r0, off, 64);
        r1 += __shfl_down(r1, off, 64);
        r2 += __shfl_down(r2, off, 64);
    }
    const int w = t >> 6;
    if ((t & 63) == 0) { red[w] = r0; red[4 + w] = r1; red[8 + w] = r2; }
    __syncthreads();

    const float nn_i  = red[0] + red[1] + red[2]  + red[3];
    const float nn_it = red[4] + red[5] + red[6]  + red[7];
    const float cross = red[8] + red[9] + red[10] + red[11];
    const float inv_ni  = 1.0f / sqrtf(nn_i  + EPS);
    const float inv_nit = 1.0f / sqrtf(nn_it + EPS);

    // Thread t: one pass over raw row t -> three dots (vs row i, row i~, self).
    const float4* __restrict__ rj  = (const float4*)(yi + t * DD);
    const float4* __restrict__ si  = (const float4*)s_yi;
    const float4* __restrict__ sit = (const float4*)s_yit;
    float4 q4  = make_float4(0.f, 0.f, 0.f, 0.f);
    float4 qt4 = make_float4(0.f, 0.f, 0.f, 0.f);
    float4 nn4 = make_float4(0.f, 0.f, 0.f, 0.f);
    #pragma unroll 8
    for (int d = 0; d < DD / 4; ++d) {
        float4 y = rj[d];
        float4 u = si[d];
        float4 v = sit[d];
        q4.x  += y.x * u.x; q4.y  += y.y * u.y; q4.z  += y.z * u.z; q4.w  += y.w * u.w;
        qt4.x += y.x * v.x; qt4.y += y.y * v.y; qt4.z += y.z * v.z; qt4.w += y.w * v.w;
        nn4.x += y.x * y.x; nn4.y += y.y * y.y; nn4.z += y.z * y.z; nn4.w += y.w * y.w;
    }
    const float q  = (q4.x  + q4.y ) + (q4.z  + q4.w );
    const float qt = (qt4.x + qt4.y) + (qt4.z + qt4.w);
    const float nn = (nn4.x + nn4.y) + (nn4.z + nn4.w);

    const float inv_nt = 1.0f / sqrtf(nn + EPS);
    const float c    = q  * inv_nt * inv_ni;
    const float ct   = qt * inv_nt * inv_nit;
    const float myv  = 0.5f * sqrtf(fmaxf(2.0f - 2.0f * c , 0.0f) + EPS);
    const float myvt = 0.5f * sqrtf(fmaxf(2.0f - 2.0f * ct, 0.0f) + EPS);
    sdis[t] = myv;
    __syncthreads();

    // Stable rank == top_k position (ties -> lower index first).
    int rank = 0;
    const float4* sd4 = (const float4*)sdis;
    #pragma unroll 8
    for (int j4 = 0; j4 < NN / 4; ++j4) {
        float4 v = sd4[j4];   // broadcast LDS read, conflict-free
        const int j = j4 * 4;
        rank += (v.x < myv || (v.x == myv && (j + 0) < t)) ? 1 : 0;
        rank += (v.y < myv || (v.y == myv && (j + 1) < t)) ? 1 : 0;
        rank += (v.z < myv || (v.z == myv && (j + 2) < t)) ? 1 : 0;
        rank += (v.w < myv || (v.w == myv && (j + 3) < t)) ? 1 : 0;
    }

    float contrib = 0.0f;
    if (rank >= 1 && rank <= KK) {          // e1 term: t is one of the 16 nbrs
        const float dd = myv - myvt;
        contrib = dd * dd - T_THRESH;
    }
    if (rank == 1) {                        // e2 hinge: t is the 2nd-NN (1st non-self)
        const float cc = cross * inv_ni * inv_nit;
        const float d_iit = 0.5f * sqrtf(fmaxf(2.0f - 2.0f * cc, 0.0f) + EPS);
        contrib += fmaxf(d_iit + M_MARGIN - myv, 0.0f);
    }

    // Block reduce + one atomic per block.
    #pragma unroll
    for (int off = 32; off > 0; off >>= 1) contrib += __shfl_down(contrib, off, 64);
    __syncthreads();                        // red[] reuse safety
    if ((t & 63) == 0) red[w] = contrib;
    __syncthreads();
    if (t == 0) atomicAdd(out, (red[0] + red[1]) + (red[2] + red[3]));
}

extern "C" void kernel_launch(void* const* d_in, const int* in_sizes, int n_in,
                              void* d_out, int out_size, void* d_ws, size_t ws_size,
                              hipStream_t stream) {
    (void)in_sizes; (void)n_in; (void)out_size; (void)d_ws; (void)ws_size;

    const float* yi  = (const float*)d_in[0];
    const float* yit = (const float*)d_in[1];
    float* out = (float*)d_out;

    hipMemsetAsync(out, 0, sizeof(float), stream);   // capture-safe zero
    blcd_fused_kernel<<<NN, 256, 0, stream>>>(yi, yit, out);
}

// Round 3
// 71.478 us; speedup vs baseline: 1.0684x; 1.0460x over previous
//
#include <hip/hip_runtime.h>
#include <math.h>

#define NN 256
#define DD 256
#define KK 16
#define M_MARGIN 0.6f
#define T_THRESH 0.0025f
#define EPS 1e-12f

// One fused kernel: block i handles row i. 512 threads: lane-pair (t, t^1)
// shares candidate j = t>>1, splitting the D-loop (interleaved float4 halves)
// and the rank scan; partials combine via __shfl_xor. Gram identity
// ||a_i - a_j||^2 = 2 - 2*(y_i.y_j)/(n_i*n_j) avoids materializing the
// normalized matrices entirely.
__global__ void __launch_bounds__(512) blcd_fused_kernel(
    const float* __restrict__ yi, const float* __restrict__ yit,
    float* __restrict__ out)
{
    __shared__ float s_yi[DD];    // raw row i
    __shared__ float s_yit[DD];   // raw row i (tilde)
    __shared__ float sdis[NN];    // dis_yii[i][:]
    __shared__ float red[24];     // 8 wave partials x 3 reduced quantities

    const int i = blockIdx.x;
    const int t = threadIdx.x;    // 0..511
    const int j = t >> 1;         // candidate row
    const int h = t & 1;          // which half of the D-range

    // Stage row i (+tilde) and reduce the three row-i norms/cross.
    float a = 0.0f, b = 0.0f;
    if (t < DD) {
        a = yi [i * DD + t];
        b = yit[i * DD + t];
        s_yi[t]  = a;
        s_yit[t] = b;
    }
    float r0 = a * a, r1 = b * b, r2 = a * b;
    #pragma unroll
    for (int off = 32; off > 0; off >>= 1) {
        r0 += __shfl_down(r0, off, 64);
        r1 += __shfl_down(r1, off, 64);
        r2 += __shfl_down(r2, off, 64);
    }
    const int w = t >> 6;                       // wave id 0..7
    if ((t & 63) == 0) { red[w] = r0; red[8 + w] = r1; red[16 + w] = r2; }
    __syncthreads();

    const float nn_i  = ((red[0]  + red[1])  + (red[2]  + red[3]))
                      + ((red[4]  + red[5])  + (red[6]  + red[7]));
    const float nn_it = ((red[8]  + red[9])  + (red[10] + red[11]))
                      + ((red[12] + red[13]) + (red[14] + red[15]));
    const float cross = ((red[16] + red[17]) + (red[18] + red[19]))
                      + ((red[20] + red[21]) + (red[22] + red[23]));
    const float inv_ni  = 1.0f / sqrtf(nn_i  + EPS);
    const float inv_nit = 1.0f / sqrtf(nn_it + EPS);

    // Half D-loop: float4 index d4 = 2k + h  (lane-pairs read contiguous 32B).
    const float4* __restrict__ rj  = (const float4*)(yi + j * DD);
    const float4* __restrict__ si  = (const float4*)s_yi;
    const float4* __restrict__ sit = (const float4*)s_yit;
    float4 q4  = make_float4(0.f, 0.f, 0.f, 0.f);
    float4 qt4 = make_float4(0.f, 0.f, 0.f, 0.f);
    float4 nn4 = make_float4(0.f, 0.f, 0.f, 0.f);
    #pragma unroll 8
    for (int k = 0; k < DD / 8; ++k) {
        const int d4 = 2 * k + h;
        float4 y = rj[d4];
        float4 u = si[d4];
        float4 v = sit[d4];
        q4.x  += y.x * u.x; q4.y  += y.y * u.y; q4.z  += y.z * u.z; q4.w  += y.w * u.w;
        qt4.x += y.x * v.x; qt4.y += y.y * v.y; qt4.z += y.z * v.z; qt4.w += y.w * v.w;
        nn4.x += y.x * y.x; nn4.y += y.y * y.y; nn4.z += y.z * y.z; nn4.w += y.w * y.w;
    }
    float q  = (q4.x  + q4.y ) + (q4.z  + q4.w );
    float qt = (qt4.x + qt4.y) + (qt4.z + qt4.w);
    float nn = (nn4.x + nn4.y) + (nn4.z + nn4.w);
    // Combine the two halves (partner lane is t^1, same wave).
    q  += __shfl_xor(q,  1, 64);
    qt += __shfl_xor(qt, 1, 64);
    nn += __shfl_xor(nn, 1, 64);

    const float inv_nt = 1.0f / sqrtf(nn + EPS);
    const float c    = q  * inv_nt * inv_ni;
    const float ct   = qt * inv_nt * inv_nit;
    const float myv  = 0.5f * sqrtf(fmaxf(2.0f - 2.0f * c , 0.0f) + EPS);
    const float myvt = 0.5f * sqrtf(fmaxf(2.0f - 2.0f * ct, 0.0f) + EPS);
    if (h == 0) sdis[j] = myv;
    __syncthreads();

    // Stable rank == top_k position (ties -> lower index first), split per pair.
    int rank = 0;
    const float4* sd4 = (const float4*)sdis;
    #pragma unroll 8
    for (int k = h * (NN / 8); k < (h + 1) * (NN / 8); ++k) {
        float4 v = sd4[k];
        const int jj = k * 4;
        rank += (v.x < myv || (v.x == myv && (jj + 0) < j)) ? 1 : 0;
        rank += (v.y < myv || (v.y == myv && (jj + 1) < j)) ? 1 : 0;
        rank += (v.z < myv || (v.z == myv && (jj + 2) < j)) ? 1 : 0;
        rank += (v.w < myv || (v.w == myv && (jj + 3) < j)) ? 1 : 0;
    }
    rank += __shfl_xor(rank, 1, 64);

    float contrib = 0.0f;
    if (h == 0) {
        if (rank >= 1 && rank <= KK) {      // e1 term: j is one of the 16 nbrs
            const float dd = myv - myvt;
            contrib = dd * dd - T_THRESH;
        }
        if (rank == 1) {                    // e2 hinge: j is the 2nd-NN
            const float cc = cross * inv_ni * inv_nit;
            const float d_iit = 0.5f * sqrtf(fmaxf(2.0f - 2.0f * cc, 0.0f) + EPS);
            contrib += fmaxf(d_iit + M_MARGIN - myv, 0.0f);
        }
    }

    // Block reduce (8 waves) + one atomic per block.
    #pragma unroll
    for (int off = 32; off > 0; off >>= 1) contrib += __shfl_down(contrib, off, 64);
    __syncthreads();                        // red[] reuse safety
    if ((t & 63) == 0) red[w] = contrib;
    __syncthreads();
    if (t == 0)
        atomicAdd(out, ((red[0] + red[1]) + (red[2] + red[3]))
                     + ((red[4] + red[5]) + (red[6] + red[7])));
}

extern "C" void kernel_launch(void* const* d_in, const int* in_sizes, int n_in,
                              void* d_out, int out_size, void* d_ws, size_t ws_size,
                              hipStream_t stream) {
    (void)in_sizes; (void)n_in; (void)out_size; (void)d_ws; (void)ws_size;

    const float* yi  = (const float*)d_in[0];
    const float* yit = (const float*)d_in[1];
    float* out = (float*)d_out;

    hipMemsetAsync(out, 0, sizeof(float), stream);   // capture-safe zero
    blcd_fused_kernel<<<NN, 512, 0, stream>>>(yi, yit, out);
}